// Round 7
// baseline (417.363 us; speedup 1.0000x reference)
//
#include <hip/hip_runtime.h>
#include <stdint.h>

// Causal GQA attention fwd, B=2 T=2048 H=32 HKV=8 D=128, fp32 in/out, bf16 MFMA compute.
//
// Round 7: same 32x32x16 swapped inner loop as round 6; occupancy fix: 8-wave
// (512-thread) blocks sharing the staged K/V tiles -> 2 blocks/CU = 16 waves/CU
// (was 8). 512 blocks; per-XCD dispatch order = qtiles {7,6,5,4} desc then {0,1,2,3}
// asc so in-order CU fill pairs complementary qtiles (sum-7 => uniform CU work).
//
//   cvt_k:  K fp32 [B,T,8,128] -> Kb bf16 [B,8,T,128], 16B-slot s stored at s^(t&7)
//   cvt_v:  V fp32 [B,T,8,128] -> VTb bf16 [B,8,tile64][d:128][kv-octet slot: s^(d&7)]
//   attn:   512 blocks x 512 thr (8 waves x 32 q rows = 256-row qtile). KVBLK=64,
//           double-buffered LDS via global_load_lds width=16.
//           QK^T swapped: S^T col=q=lane&31, row kv=(r&3)+8*(r>>2)+4*(lane>>5);
//           lane-local softmax (log2 domain), T13 defer-rescale, diagonal-only mask;
//           P -> PV B-operand in-register via 4 shfl_xor(32)+selects per 32-kv subtile.

typedef __attribute__((ext_vector_type(8))) __bf16 bf16x8;
typedef __attribute__((ext_vector_type(16))) float f32x16;

#define QSCALE (0.08838834764831845f * 1.4426950408889634f)

// ---------------- pre-pass: K convert + swizzle ----------------
__global__ __launch_bounds__(256) void cvt_k(const float* __restrict__ k,
                                             unsigned short* __restrict__ kb) {
    unsigned tid = blockIdx.x * 256u + threadIdx.x;
    unsigned s = tid & 15u;
    unsigned h = (tid >> 4) & 7u;
    unsigned t = (tid >> 7) & 2047u;
    unsigned b = tid >> 18;
    const float4* src = (const float4*)(k + (size_t)tid * 8u);
    float4 f0 = src[0], f1 = src[1];
    bf16x8 r;
    r[0] = (__bf16)f0.x; r[1] = (__bf16)f0.y; r[2] = (__bf16)f0.z; r[3] = (__bf16)f0.w;
    r[4] = (__bf16)f1.x; r[5] = (__bf16)f1.y; r[6] = (__bf16)f1.z; r[7] = (__bf16)f1.w;
    size_t o = ((size_t)((b * 8u + h) * 2048u + t) * 16u + (s ^ (t & 7u))) * 8u;
    *(bf16x8*)(kb + o) = r;
}

// ---------------- pre-pass: V convert + transpose + tile ----------------
// VTb layout: [b][h][tile(32 of 64kv)][d(128)][slot(8)][elem(8)], slot holds kv
// octet (slot*8..+8) of the tile, stored at slot ^ (d&7) for conflict-free b128.
__global__ __launch_bounds__(256) void cvt_v(const float* __restrict__ v,
                                             unsigned short* __restrict__ vtb) {
    unsigned tid = blockIdx.x * 256u + threadIdx.x;
    unsigned d = tid & 127u;
    unsigned slot = (tid >> 7) & 7u;
    unsigned tile = (tid >> 10) & 31u;
    unsigned h = (tid >> 15) & 7u;
    unsigned b = tid >> 18;
    const float* src = v + ((size_t)(b * 2048u + tile * 64u + slot * 8u) * 8u + h) * 128u + d;
    bf16x8 r;
#pragma unroll
    for (int j = 0; j < 8; ++j) r[j] = (__bf16)src[(size_t)j * 1024u];
    size_t o = (((size_t)((b * 8u + h) * 32u + tile) * 128u + d) * 8u + (slot ^ (d & 7u))) * 8u;
    *(bf16x8*)(vtb + o) = r;
}

// ---------------- main attention kernel ----------------
__device__ inline void load16_lds(const void* g, void* l) {
    __builtin_amdgcn_global_load_lds(
        (__attribute__((address_space(1))) void*)(g),
        (__attribute__((address_space(3))) void*)(l), 16, 0, 0);
}

union BW2 { unsigned u; __bf16 h[2]; };
union BW8 { unsigned u[4]; bf16x8 v; };

__global__ __launch_bounds__(512, 4) void attn_fwd(const float* __restrict__ qg,
                                                   const unsigned short* __restrict__ kb,
                                                   const unsigned short* __restrict__ vtb,
                                                   float* __restrict__ outg) {
    __shared__ __align__(16) unsigned short Klds[2][64 * 128];   // 32 KB
    __shared__ __align__(16) unsigned short Vlds[2][128 * 64];   // 32 KB

    // Decode: bid&7 = XCD = kvh. pos 0..63 within XCD: first 32 -> qtile 7-(pos>>3)
    // (desc), second 32 -> qtile (pos-32)>>3 (asc) => in-order CU fill pairs sum-7.
    int bid = blockIdx.x;
    int kvh = bid & 7;
    int pos = bid >> 3;                // 0..63
    int qtile = (pos < 32) ? (7 - (pos >> 3)) : ((pos - 32) >> 3);
    int sub = pos & 7;
    int b = sub & 1;
    int h = kvh * 4 + (sub >> 1);

    int tid = threadIdx.x;
    int lane = tid & 63;
    int w = tid >> 6;                  // 0..7
    int lq = lane & 31;
    int hi = lane >> 5;
    bool bhi = (hi != 0);
    int q0w = qtile * 256 + w * 32;
    int qmaxw = q0w + 31;
    int nt = 4 * (qtile + 1);

    const unsigned short* kTile = kb + (size_t)(b * 8 + kvh) * 2048u * 128u;
    const unsigned short* vTile = vtb + (size_t)(b * 8 + kvh) * 32u * 8192u;

    auto stage = [&](int t, int buf) {
        const char* ks = (const char*)(kTile + (size_t)t * 8192u);   // 16 KB contiguous
        const char* vs = (const char*)(vTile + (size_t)t * 8192u);   // 16 KB contiguous
#pragma unroll
        for (int i = 0; i < 2; ++i) {
            load16_lds(ks + (i * 512 + tid) * 16, &Klds[buf][(i * 512 + tid) * 8]);
            load16_lds(vs + (i * 512 + tid) * 16, &Vlds[buf][(i * 512 + tid) * 8]);
        }
    };

    stage(0, 0);

    // Q B-frags: lane holds q-row = q0w+lq, d-octet (lane>>5) of each 16-chunk.
    bf16x8 qf[8];
    {
        const float* qp = qg + ((size_t)(b * 2048 + q0w + lq) * 32u + h) * 128u;
#pragma unroll
        for (int c = 0; c < 8; ++c) {
            int d0 = c * 16 + hi * 8;
            float4 f0 = *(const float4*)(qp + d0);
            float4 f1 = *(const float4*)(qp + d0 + 4);
            qf[c][0] = (__bf16)(f0.x * QSCALE); qf[c][1] = (__bf16)(f0.y * QSCALE);
            qf[c][2] = (__bf16)(f0.z * QSCALE); qf[c][3] = (__bf16)(f0.w * QSCALE);
            qf[c][4] = (__bf16)(f1.x * QSCALE); qf[c][5] = (__bf16)(f1.y * QSCALE);
            qf[c][6] = (__bf16)(f1.z * QSCALE); qf[c][7] = (__bf16)(f1.w * QSCALE);
        }
    }

    f32x16 acc[4];
#pragma unroll
    for (int dt = 0; dt < 4; ++dt)
#pragma unroll
        for (int r = 0; r < 16; ++r) acc[dt][r] = 0.f;
    float mrun = -1e30f, lrun = 0.f;

    for (int t = 0; t < nt; ++t) {
        asm volatile("s_waitcnt vmcnt(0)" ::: "memory");
        __syncthreads();
        int buf = t & 1;
        if (t + 1 < nt) stage(t + 1, buf ^ 1);
        int kv0 = t * 64;
        if (kv0 <= qmaxw) {                          // wave-uniform
            bool s1a = (kv0 + 32 <= qmaxw);          // second 32-kv subtile active
            // ---- QK^T
            f32x16 st0, st1;
#pragma unroll
            for (int r = 0; r < 16; ++r) { st0[r] = 0.f; st1[r] = 0.f; }
            __builtin_amdgcn_s_setprio(1);
#pragma unroll
            for (int c = 0; c < 8; ++c) {
                int so = ((2 * c + hi) ^ (lq & 7)) << 3;
                bf16x8 kf0 = *(const bf16x8*)&Klds[buf][lq * 128 + so];
                st0 = __builtin_amdgcn_mfma_f32_32x32x16_bf16(kf0, qf[c], st0, 0, 0, 0);
            }
            if (s1a) {
#pragma unroll
                for (int c = 0; c < 8; ++c) {
                    int so = ((2 * c + hi) ^ (lq & 7)) << 3;
                    bf16x8 kf1 = *(const bf16x8*)&Klds[buf][(32 + lq) * 128 + so];
                    st1 = __builtin_amdgcn_mfma_f32_32x32x16_bf16(kf1, qf[c], st1, 0, 0, 0);
                }
            }
            __builtin_amdgcn_s_setprio(0);
            // ---- causal mask (diagonal tiles only); q = q0w+lq, kv row per reg
            int qg_ = q0w + lq;
            if (kv0 + 31 > q0w) {
#pragma unroll
                for (int r = 0; r < 16; ++r) {
                    int kvl = (r & 3) + 8 * (r >> 2) + 4 * hi;
                    if (kv0 + kvl > qg_) st0[r] = -1e30f;
                }
            }
            if (s1a && (kv0 + 63 > q0w)) {
#pragma unroll
                for (int r = 0; r < 16; ++r) {
                    int kvl = (r & 3) + 8 * (r >> 2) + 4 * hi;
                    if (kv0 + 32 + kvl > qg_) st1[r] = -1e30f;
                }
            }
            // ---- lane-local max (combine lane<->lane+32 once)
            float m = -1e30f;
#pragma unroll
            for (int r = 0; r < 16; ++r) m = fmaxf(m, st0[r]);
            if (s1a)
#pragma unroll
                for (int r = 0; r < 16; ++r) m = fmaxf(m, st1[r]);
            m = fmaxf(m, __shfl_xor(m, 32));
            // ---- T13 defer-rescale (lane-local fac, no broadcast)
            if (!__all(m <= mrun + 8.f)) {
                float mn = fmaxf(mrun, m);
                float fac = exp2f(mrun - mn);
                lrun *= fac; mrun = mn;
#pragma unroll
                for (int dt = 0; dt < 4; ++dt)
#pragma unroll
                    for (int r = 0; r < 16; ++r) acc[dt][r] *= fac;
            }
            // ---- exp2 + lane-local sum
            float ps = 0.f;
#pragma unroll
            for (int r = 0; r < 16; ++r) { st0[r] = exp2f(st0[r] - mrun); ps += st0[r]; }
            if (s1a)
#pragma unroll
                for (int r = 0; r < 16; ++r) { st1[r] = exp2f(st1[r] - mrun); ps += st1[r]; }
            ps += __shfl_xor(ps, 32);
            lrun += ps;
            // ---- PV per 32-kv subtile: pack P to bf16 words, exchange lane<->lane+32,
            //      feed as B-operand; A = V^T frags from LDS.
#pragma unroll
            for (int s = 0; s < 2; ++s) {
                if (s == 1 && !s1a) break;
                const f32x16& stv = (s == 0) ? st0 : st1;
                unsigned wv[8];
#pragma unroll
                for (int i = 0; i < 8; ++i) {
                    BW2 t2; t2.h[0] = (__bf16)stv[2 * i]; t2.h[1] = (__bf16)stv[2 * i + 1];
                    wv[i] = t2.u;
                }
                unsigned u0 = bhi ? wv[0] : wv[2]; u0 = __shfl_xor(u0, 32);
                unsigned u1 = bhi ? wv[1] : wv[3]; u1 = __shfl_xor(u1, 32);
                unsigned u2 = bhi ? wv[4] : wv[6]; u2 = __shfl_xor(u2, 32);
                unsigned u3 = bhi ? wv[5] : wv[7]; u3 = __shfl_xor(u3, 32);
                BW8 pb0, pb1;
                pb0.u[0] = bhi ? u0 : wv[0]; pb0.u[1] = bhi ? u1 : wv[1];
                pb0.u[2] = bhi ? wv[2] : u0; pb0.u[3] = bhi ? wv[3] : u1;
                pb1.u[0] = bhi ? u2 : wv[4]; pb1.u[1] = bhi ? u3 : wv[5];
                pb1.u[2] = bhi ? wv[6] : u2; pb1.u[3] = bhi ? wv[7] : u3;
                __builtin_amdgcn_s_setprio(1);
#pragma unroll
                for (int dt = 0; dt < 4; ++dt) {
                    int drow = dt * 32 + lq;
                    int so0 = (((4 * s + hi) ^ (drow & 7)) << 3);
                    int so1 = (((4 * s + 2 + hi) ^ (drow & 7)) << 3);
                    bf16x8 vf0 = *(const bf16x8*)&Vlds[buf][drow * 64 + so0];
                    acc[dt] = __builtin_amdgcn_mfma_f32_32x32x16_bf16(vf0, pb0.v, acc[dt], 0, 0, 0);
                    bf16x8 vf1 = *(const bf16x8*)&Vlds[buf][drow * 64 + so1];
                    acc[dt] = __builtin_amdgcn_mfma_f32_32x32x16_bf16(vf1, pb1.v, acc[dt], 0, 0, 0);
                }
                __builtin_amdgcn_s_setprio(0);
            }
        }
    }

    // ---- epilogue: lane-local 1/l, f32x4 stores (d-quads are consecutive)
    float il = 1.0f / lrun;
    float* ob = outg + ((size_t)(b * 2048 + q0w + lq) * 32u + h) * 128u;
#pragma unroll
    for (int dt = 0; dt < 4; ++dt)
#pragma unroll
        for (int rq = 0; rq < 4; ++rq) {
            int d = dt * 32 + rq * 8 + hi * 4;
            float4 o4 = { acc[dt][rq * 4 + 0] * il, acc[dt][rq * 4 + 1] * il,
                          acc[dt][rq * 4 + 2] * il, acc[dt][rq * 4 + 3] * il };
            *(float4*)(ob + d) = o4;
        }
}

extern "C" void kernel_launch(void* const* d_in, const int* in_sizes, int n_in,
                              void* d_out, int out_size, void* d_ws, size_t ws_size,
                              hipStream_t stream) {
    const float* q = (const float*)d_in[0];
    const float* k = (const float*)d_in[1];
    const float* v = (const float*)d_in[2];
    float* out = (float*)d_out;
    unsigned short* kbuf = (unsigned short*)d_ws;                    // 8 MB bf16 K
    unsigned short* vbuf = kbuf + (size_t)2 * 8 * 2048 * 128;        // 8 MB bf16 V^T (tiled)
    cvt_k<<<2048, 256, 0, stream>>>(k, kbuf);
    cvt_v<<<2048, 256, 0, stream>>>(v, vbuf);
    attn_fwd<<<512, 512, 0, stream>>>(q, kbuf, vbuf, out);
}

// Round 8
// 158.581 us; speedup vs baseline: 2.6319x; 2.6319x over previous
//
#include <hip/hip_runtime.h>
#include <stdint.h>

// Causal GQA attention fwd, B=2 T=2048 H=32 HKV=8 D=128, fp32 in/out, bf16 MFMA compute.
//
// Round 8: round-7 structure with the launch-bounds fix: __launch_bounds__(512, 2).
// Round 7's (512,4) meant min 4 waves/EU -> 128-reg cap -> ~80 regs spilled ->
// 1.3GB scratch traffic (FETCH 601MB/WRITE 708MB). (512,2) caps at 256 regs
// (kernel uses ~88) -> no spill; occupancy = 2 blocks/CU x 8 waves = 16 waves/CU.
//
//   cvt_k:  K fp32 [B,T,8,128] -> Kb bf16 [B,8,T,128], 16B-slot s stored at s^(t&7)
//   cvt_v:  V fp32 [B,T,8,128] -> VTb bf16 [B,8,tile64][d:128][kv-octet slot: s^(d&7)]
//   attn:   512 blocks x 512 thr (8 waves x 32 q rows = 256-row qtile). KVBLK=64,
//           double-buffered LDS via global_load_lds width=16.
//           QK^T swapped: S^T col=q=lane&31, row kv=(r&3)+8*(r>>2)+4*(lane>>5);
//           lane-local softmax (log2 domain), T13 defer-rescale, diagonal-only mask;
//           P -> PV B-operand in-register via 4 shfl_xor(32)+selects per 32-kv subtile.

typedef __attribute__((ext_vector_type(8))) __bf16 bf16x8;
typedef __attribute__((ext_vector_type(16))) float f32x16;

#define QSCALE (0.08838834764831845f * 1.4426950408889634f)

// ---------------- pre-pass: K convert + swizzle ----------------
__global__ __launch_bounds__(256) void cvt_k(const float* __restrict__ k,
                                             unsigned short* __restrict__ kb) {
    unsigned tid = blockIdx.x * 256u + threadIdx.x;
    unsigned s = tid & 15u;
    unsigned h = (tid >> 4) & 7u;
    unsigned t = (tid >> 7) & 2047u;
    unsigned b = tid >> 18;
    const float4* src = (const float4*)(k + (size_t)tid * 8u);
    float4 f0 = src[0], f1 = src[1];
    bf16x8 r;
    r[0] = (__bf16)f0.x; r[1] = (__bf16)f0.y; r[2] = (__bf16)f0.z; r[3] = (__bf16)f0.w;
    r[4] = (__bf16)f1.x; r[5] = (__bf16)f1.y; r[6] = (__bf16)f1.z; r[7] = (__bf16)f1.w;
    size_t o = ((size_t)((b * 8u + h) * 2048u + t) * 16u + (s ^ (t & 7u))) * 8u;
    *(bf16x8*)(kb + o) = r;
}

// ---------------- pre-pass: V convert + transpose + tile ----------------
// VTb layout: [b][h][tile(32 of 64kv)][d(128)][slot(8)][elem(8)], slot holds kv
// octet (slot*8..+8) of the tile, stored at slot ^ (d&7) for conflict-free b128.
__global__ __launch_bounds__(256) void cvt_v(const float* __restrict__ v,
                                             unsigned short* __restrict__ vtb) {
    unsigned tid = blockIdx.x * 256u + threadIdx.x;
    unsigned d = tid & 127u;
    unsigned slot = (tid >> 7) & 7u;
    unsigned tile = (tid >> 10) & 31u;
    unsigned h = (tid >> 15) & 7u;
    unsigned b = tid >> 18;
    const float* src = v + ((size_t)(b * 2048u + tile * 64u + slot * 8u) * 8u + h) * 128u + d;
    bf16x8 r;
#pragma unroll
    for (int j = 0; j < 8; ++j) r[j] = (__bf16)src[(size_t)j * 1024u];
    size_t o = (((size_t)((b * 8u + h) * 32u + tile) * 128u + d) * 8u + (slot ^ (d & 7u))) * 8u;
    *(bf16x8*)(vtb + o) = r;
}

// ---------------- main attention kernel ----------------
__device__ inline void load16_lds(const void* g, void* l) {
    __builtin_amdgcn_global_load_lds(
        (__attribute__((address_space(1))) void*)(g),
        (__attribute__((address_space(3))) void*)(l), 16, 0, 0);
}

union BW2 { unsigned u; __bf16 h[2]; };
union BW8 { unsigned u[4]; bf16x8 v; };

__global__ __launch_bounds__(512, 2) void attn_fwd(const float* __restrict__ qg,
                                                   const unsigned short* __restrict__ kb,
                                                   const unsigned short* __restrict__ vtb,
                                                   float* __restrict__ outg) {
    __shared__ __align__(16) unsigned short Klds[2][64 * 128];   // 32 KB
    __shared__ __align__(16) unsigned short Vlds[2][128 * 64];   // 32 KB

    // Decode: bid&7 = XCD = kvh. pos 0..63 within XCD: first 32 -> qtile 7-(pos>>3)
    // (desc), second 32 -> qtile (pos-32)>>3 (asc) => in-order CU fill pairs sum-7.
    int bid = blockIdx.x;
    int kvh = bid & 7;
    int pos = bid >> 3;                // 0..63
    int qtile = (pos < 32) ? (7 - (pos >> 3)) : ((pos - 32) >> 3);
    int sub = pos & 7;
    int b = sub & 1;
    int h = kvh * 4 + (sub >> 1);

    int tid = threadIdx.x;
    int lane = tid & 63;
    int w = tid >> 6;                  // 0..7
    int lq = lane & 31;
    int hi = lane >> 5;
    bool bhi = (hi != 0);
    int q0w = qtile * 256 + w * 32;
    int qmaxw = q0w + 31;
    int nt = 4 * (qtile + 1);

    const unsigned short* kTile = kb + (size_t)(b * 8 + kvh) * 2048u * 128u;
    const unsigned short* vTile = vtb + (size_t)(b * 8 + kvh) * 32u * 8192u;

    auto stage = [&](int t, int buf) {
        const char* ks = (const char*)(kTile + (size_t)t * 8192u);   // 16 KB contiguous
        const char* vs = (const char*)(vTile + (size_t)t * 8192u);   // 16 KB contiguous
#pragma unroll
        for (int i = 0; i < 2; ++i) {
            load16_lds(ks + (i * 512 + tid) * 16, &Klds[buf][(i * 512 + tid) * 8]);
            load16_lds(vs + (i * 512 + tid) * 16, &Vlds[buf][(i * 512 + tid) * 8]);
        }
    };

    stage(0, 0);

    // Q B-frags: lane holds q-row = q0w+lq, d-octet (lane>>5) of each 16-chunk.
    bf16x8 qf[8];
    {
        const float* qp = qg + ((size_t)(b * 2048 + q0w + lq) * 32u + h) * 128u;
#pragma unroll
        for (int c = 0; c < 8; ++c) {
            int d0 = c * 16 + hi * 8;
            float4 f0 = *(const float4*)(qp + d0);
            float4 f1 = *(const float4*)(qp + d0 + 4);
            qf[c][0] = (__bf16)(f0.x * QSCALE); qf[c][1] = (__bf16)(f0.y * QSCALE);
            qf[c][2] = (__bf16)(f0.z * QSCALE); qf[c][3] = (__bf16)(f0.w * QSCALE);
            qf[c][4] = (__bf16)(f1.x * QSCALE); qf[c][5] = (__bf16)(f1.y * QSCALE);
            qf[c][6] = (__bf16)(f1.z * QSCALE); qf[c][7] = (__bf16)(f1.w * QSCALE);
        }
    }

    f32x16 acc[4];
#pragma unroll
    for (int dt = 0; dt < 4; ++dt)
#pragma unroll
        for (int r = 0; r < 16; ++r) acc[dt][r] = 0.f;
    float mrun = -1e30f, lrun = 0.f;

    for (int t = 0; t < nt; ++t) {
        asm volatile("s_waitcnt vmcnt(0)" ::: "memory");
        __syncthreads();
        int buf = t & 1;
        if (t + 1 < nt) stage(t + 1, buf ^ 1);
        int kv0 = t * 64;
        if (kv0 <= qmaxw) {                          // wave-uniform
            bool s1a = (kv0 + 32 <= qmaxw);          // second 32-kv subtile active
            // ---- QK^T
            f32x16 st0, st1;
#pragma unroll
            for (int r = 0; r < 16; ++r) { st0[r] = 0.f; st1[r] = 0.f; }
            __builtin_amdgcn_s_setprio(1);
#pragma unroll
            for (int c = 0; c < 8; ++c) {
                int so = ((2 * c + hi) ^ (lq & 7)) << 3;
                bf16x8 kf0 = *(const bf16x8*)&Klds[buf][lq * 128 + so];
                st0 = __builtin_amdgcn_mfma_f32_32x32x16_bf16(kf0, qf[c], st0, 0, 0, 0);
            }
            if (s1a) {
#pragma unroll
                for (int c = 0; c < 8; ++c) {
                    int so = ((2 * c + hi) ^ (lq & 7)) << 3;
                    bf16x8 kf1 = *(const bf16x8*)&Klds[buf][(32 + lq) * 128 + so];
                    st1 = __builtin_amdgcn_mfma_f32_32x32x16_bf16(kf1, qf[c], st1, 0, 0, 0);
                }
            }
            __builtin_amdgcn_s_setprio(0);
            // ---- causal mask (diagonal tiles only); q = q0w+lq, kv row per reg
            int qg_ = q0w + lq;
            if (kv0 + 31 > q0w) {
#pragma unroll
                for (int r = 0; r < 16; ++r) {
                    int kvl = (r & 3) + 8 * (r >> 2) + 4 * hi;
                    if (kv0 + kvl > qg_) st0[r] = -1e30f;
                }
            }
            if (s1a && (kv0 + 63 > q0w)) {
#pragma unroll
                for (int r = 0; r < 16; ++r) {
                    int kvl = (r & 3) + 8 * (r >> 2) + 4 * hi;
                    if (kv0 + 32 + kvl > qg_) st1[r] = -1e30f;
                }
            }
            // ---- lane-local max (combine lane<->lane+32 once)
            float m = -1e30f;
#pragma unroll
            for (int r = 0; r < 16; ++r) m = fmaxf(m, st0[r]);
            if (s1a)
#pragma unroll
                for (int r = 0; r < 16; ++r) m = fmaxf(m, st1[r]);
            m = fmaxf(m, __shfl_xor(m, 32));
            // ---- T13 defer-rescale (lane-local fac, no broadcast)
            if (!__all(m <= mrun + 8.f)) {
                float mn = fmaxf(mrun, m);
                float fac = exp2f(mrun - mn);
                lrun *= fac; mrun = mn;
#pragma unroll
                for (int dt = 0; dt < 4; ++dt)
#pragma unroll
                    for (int r = 0; r < 16; ++r) acc[dt][r] *= fac;
            }
            // ---- exp2 + lane-local sum
            float ps = 0.f;
#pragma unroll
            for (int r = 0; r < 16; ++r) { st0[r] = exp2f(st0[r] - mrun); ps += st0[r]; }
            if (s1a)
#pragma unroll
                for (int r = 0; r < 16; ++r) { st1[r] = exp2f(st1[r] - mrun); ps += st1[r]; }
            ps += __shfl_xor(ps, 32);
            lrun += ps;
            // ---- PV per 32-kv subtile: pack P to bf16 words, exchange lane<->lane+32,
            //      feed as B-operand; A = V^T frags from LDS.
#pragma unroll
            for (int s = 0; s < 2; ++s) {
                if (s == 1 && !s1a) break;
                const f32x16& stv = (s == 0) ? st0 : st1;
                unsigned wv[8];
#pragma unroll
                for (int i = 0; i < 8; ++i) {
                    BW2 t2; t2.h[0] = (__bf16)stv[2 * i]; t2.h[1] = (__bf16)stv[2 * i + 1];
                    wv[i] = t2.u;
                }
                unsigned u0 = bhi ? wv[0] : wv[2]; u0 = __shfl_xor(u0, 32);
                unsigned u1 = bhi ? wv[1] : wv[3]; u1 = __shfl_xor(u1, 32);
                unsigned u2 = bhi ? wv[4] : wv[6]; u2 = __shfl_xor(u2, 32);
                unsigned u3 = bhi ? wv[5] : wv[7]; u3 = __shfl_xor(u3, 32);
                BW8 pb0, pb1;
                pb0.u[0] = bhi ? u0 : wv[0]; pb0.u[1] = bhi ? u1 : wv[1];
                pb0.u[2] = bhi ? wv[2] : u0; pb0.u[3] = bhi ? wv[3] : u1;
                pb1.u[0] = bhi ? u2 : wv[4]; pb1.u[1] = bhi ? u3 : wv[5];
                pb1.u[2] = bhi ? wv[6] : u2; pb1.u[3] = bhi ? wv[7] : u3;
                __builtin_amdgcn_s_setprio(1);
#pragma unroll
                for (int dt = 0; dt < 4; ++dt) {
                    int drow = dt * 32 + lq;
                    int so0 = (((4 * s + hi) ^ (drow & 7)) << 3);
                    int so1 = (((4 * s + 2 + hi) ^ (drow & 7)) << 3);
                    bf16x8 vf0 = *(const bf16x8*)&Vlds[buf][drow * 64 + so0];
                    acc[dt] = __builtin_amdgcn_mfma_f32_32x32x16_bf16(vf0, pb0.v, acc[dt], 0, 0, 0);
                    bf16x8 vf1 = *(const bf16x8*)&Vlds[buf][drow * 64 + so1];
                    acc[dt] = __builtin_amdgcn_mfma_f32_32x32x16_bf16(vf1, pb1.v, acc[dt], 0, 0, 0);
                }
                __builtin_amdgcn_s_setprio(0);
            }
        }
    }

    // ---- epilogue: lane-local 1/l, f32x4 stores (d-quads are consecutive)
    float il = 1.0f / lrun;
    float* ob = outg + ((size_t)(b * 2048 + q0w + lq) * 32u + h) * 128u;
#pragma unroll
    for (int dt = 0; dt < 4; ++dt)
#pragma unroll
        for (int rq = 0; rq < 4; ++rq) {
            int d = dt * 32 + rq * 8 + hi * 4;
            float4 o4 = { acc[dt][rq * 4 + 0] * il, acc[dt][rq * 4 + 1] * il,
                          acc[dt][rq * 4 + 2] * il, acc[dt][rq * 4 + 3] * il };
            *(float4*)(ob + d) = o4;
        }
}

extern "C" void kernel_launch(void* const* d_in, const int* in_sizes, int n_in,
                              void* d_out, int out_size, void* d_ws, size_t ws_size,
                              hipStream_t stream) {
    const float* q = (const float*)d_in[0];
    const float* k = (const float*)d_in[1];
    const float* v = (const float*)d_in[2];
    float* out = (float*)d_out;
    unsigned short* kbuf = (unsigned short*)d_ws;                    // 8 MB bf16 K
    unsigned short* vbuf = kbuf + (size_t)2 * 8 * 2048 * 128;        // 8 MB bf16 V^T (tiled)
    cvt_k<<<2048, 256, 0, stream>>>(k, kbuf);
    cvt_v<<<2048, 256, 0, stream>>>(v, vbuf);
    attn_fwd<<<512, 512, 0, stream>>>(q, kbuf, vbuf, out);
}